// Round 1
// baseline (350.352 us; speedup 1.0000x reference)
//
#include <hip/hip_runtime.h>
#include <cstdint>
#include <cstddef>

#define BB 4
#define NN 1024
#define EMB_ 64
#define NH_ 8
#define BH_ (BB*NH_)
#define HID_ 256
#define K_ 8
#define NPTS_ 64

// ---------------- threefry2x32 (JAX-compatible, 20 rounds) ----------------
__host__ __device__ inline void tf2x32(uint32_t k0, uint32_t k1, uint32_t c0, uint32_t c1,
                                       uint32_t &o0, uint32_t &o1) {
  uint32_t ks2 = k0 ^ k1 ^ 0x1BD11BDAu;
  uint32_t x0 = c0 + k0, x1 = c1 + k1;
#define TFR(r) { x0 += x1; x1 = (x1 << (r)) | (x1 >> (32 - (r))); x1 ^= x0; }
  TFR(13) TFR(15) TFR(26) TFR(6)
  x0 += k1;  x1 += ks2 + 1u;
  TFR(17) TFR(29) TFR(16) TFR(24)
  x0 += ks2; x1 += k0 + 2u;
  TFR(13) TFR(15) TFR(26) TFR(6)
  x0 += k0;  x1 += k1 + 3u;
  TFR(17) TFR(29) TFR(16) TFR(24)
  x0 += k1;  x1 += ks2 + 4u;
  TFR(13) TFR(15) TFR(26) TFR(6)
  x0 += ks2; x1 += k0 + 5u;
#undef TFR
  o0 = x0; o1 = x1;
}

// partitionable random_bits, 32-bit: y0 ^ y1 of TF(key, (0, flat_index))
__device__ inline uint32_t tf_bits(uint32_t k0, uint32_t k1, uint32_t idx) {
  uint32_t a, b;
  tf2x32(k0, k1, 0u, idx, a, b);
  return a ^ b;
}

__device__ inline float softplusf(float v) {
  // jax.nn.softplus = logaddexp(x, 0) = max(x,0) + log1p(exp(-|x|))
  return fmaxf(v, 0.f) + log1pf(expf(-fabsf(v)));
}

// ---------------- K1: QKV projection ----------------
#define ROWS1 16
__global__ void qkv_kernel(const float* __restrict__ x,
                           const float* __restrict__ Wq, const float* __restrict__ Wk,
                           const float* __restrict__ Wv,
                           float* __restrict__ q, float* __restrict__ k, float* __restrict__ v) {
  __shared__ float xs[ROWS1][EMB_];
  const int block0 = blockIdx.x * ROWS1; // global row (b*N+n)
  const int t = threadIdx.x;             // 256 threads
  for (int i = t; i < ROWS1 * EMB_; i += 256) xs[i / EMB_][i % EMB_] = x[(size_t)block0 * EMB_ + i];
  __syncthreads();
  const float qkscale = 0.3535533905932738f; // 64^-0.25

  auto dmat = [&](const float* __restrict__ W, float* __restrict__ o, float sc) {
    for (int half = 0; half < 2; half++) {
      const int c = half * 256 + t; // 0..511
      float acc[ROWS1];
#pragma unroll
      for (int r = 0; r < ROWS1; r++) acc[r] = 0.f;
      for (int i = 0; i < EMB_; i++) {
        const float wv = W[i * 512 + c];
#pragma unroll
        for (int r = 0; r < ROWS1; r++) acc[r] += xs[r][i] * wv;
      }
      const int h = c >> 6, j = c & 63;
#pragma unroll
      for (int r = 0; r < ROWS1; r++) {
        const int gr = block0 + r;
        const int b = gr >> 10, n = gr & 1023;
        o[(((size_t)(b * NH_ + h) * NN + n)) * EMB_ + j] = acc[r] * sc;
      }
    }
  };
  dmat(Wq, q, qkscale);
  dmat(Wk, k, qkscale);
  dmat(Wv, v, 1.0f);
}

// ---------------- K2: MLP + point generation + weights ----------------
__global__ void points_kernel(const float* __restrict__ x,
                              const float* __restrict__ Wp1, const float* __restrict__ bp1,
                              const float* __restrict__ Wp2, const float* __restrict__ bp2,
                              const float* __restrict__ mvalues,
                              int* __restrict__ prc, float* __restrict__ pw,
                              int* __restrict__ counts,
                              uint32_t kg0, uint32_t kg1, uint32_t kl0, uint32_t kl1) {
  __shared__ float xs[EMB_];
  __shared__ float hs[HID_];
  __shared__ float ps[16];
  __shared__ float meanv[K_], invsig[K_];
  __shared__ int flv[K_];
  __shared__ int pk[NPTS_];

  const int bn = blockIdx.x;          // b*N + n
  const int b = bn >> 10, n = bn & 1023;
  const int lane = threadIdx.x;       // 64 threads

  xs[lane] = x[(size_t)bn * EMB_ + lane];
  __syncthreads();

  // h = relu(x @ Wp1 + bp1), 4 columns per lane
#pragma unroll
  for (int cc = 0; cc < 4; cc++) {
    const int c = cc * 64 + lane;
    float a = bp1[c];
    for (int i = 0; i < EMB_; i++) a += xs[i] * Wp1[i * HID_ + c];
    hs[c] = fmaxf(a, 0.f);
  }
  __syncthreads();

  if (lane < 16) {
    float a = bp2[lane];
    for (int c = 0; c < HID_; c++) a += hs[c] * Wp2[c * 16 + lane];
    ps[lane] = a;
  }
  __syncthreads();

  if (lane < K_) {
    const float rm = ps[lane], rs = ps[K_ + lane];
    float mean = (float)n - softplusf(rm);
    mean = fminf(fmaxf(mean, 0.f), (float)(NN - 1));
    const float sig = softplusf(rs + 2.0f) + 1e-6f;
    meanv[lane] = mean;
    invsig[lane] = 1.f / sig;
    flv[lane] = (int)floorf(mean);
  }
  __syncthreads();

  // one lane per point: p = k*8 + j ; j<4 corners, j=4,5 glob, j=6,7 loc
  const int kk = lane >> 3, j = lane & 7;
  const int fl = flv[kk];
  int row, col;
  if (j < 4) {
    row = fl + (j >> 1);
    col = fl + (j & 1);
  } else if (j < 6) {
    const int g = j - 4;
    const uint32_t base = ((uint32_t)(bn * K_ + kk) * 2u + (uint32_t)g) * 2u;
    row = (int)(tf_bits(kg0, kg1, base + 0u) & 1023u);
    col = (int)(tf_bits(kg0, kg1, base + 1u) & 1023u);
  } else {
    const int a = j - 6;
    const uint32_t base = ((uint32_t)(bn * K_ + kk) * 2u + (uint32_t)a) * 2u;
    row = fl - 1 + (int)(tf_bits(kl0, kl1, base + 0u) & 1u);
    col = fl - 1 + (int)(tf_bits(kl0, kl1, base + 1u) & 1u);
  }
  row = min(max(row, 0), NN - 1);
  col = min(max(col, 0), NN - 1);
  const int packed = (row << 16) | col;
  pk[lane] = packed;
  __syncthreads();

  bool dup = false;
  for (int p2 = 0; p2 < lane; p2++)
    if (pk[p2] == packed) dup = true;

  const float frow = (float)row, fcol = (float)col;
  float dens[K_];
#pragma unroll
  for (int qd = 0; qd < K_; qd++) {
    const float dx = (frow - meanv[qd]) * invsig[qd];
    const float dy = (fcol - meanv[qd]) * invsig[qd];
    dens[qd] = dup ? 0.f : expf(-0.5f * (dx * dx + dy * dy));
  }
  float wsum = 0.f;
#pragma unroll
  for (int qd = 0; qd < K_; qd++) {
    float s = dens[qd];
    for (int d = 1; d < 64; d <<= 1) s += __shfl_xor(s, d);
    wsum += dens[qd] / s;
  }
  const float w = mvalues[n] * wsum;

  prc[(size_t)bn * NPTS_ + lane] = packed;
  pw[(size_t)bn * NPTS_ + lane] = w;
  atomicAdd(&counts[b * NN + row], 1);
}

// ---------------- K3: per-b exclusive scan of row counts ----------------
__global__ void scan_kernel(const int* __restrict__ counts,
                            int* __restrict__ offs, int* __restrict__ cursor) {
  __shared__ int sd[NN];
  const int b = blockIdx.x, t = threadIdx.x; // 1024 threads
  const int v = counts[b * NN + t];
  sd[t] = v;
  __syncthreads();
  for (int d = 1; d < NN; d <<= 1) {
    const int add = (t >= d) ? sd[t - d] : 0;
    __syncthreads();
    sd[t] += add;
    __syncthreads();
  }
  const int excl = sd[t] - v;
  offs[b * NN + t] = excl;
  cursor[b * NN + t] = excl;
}

// ---------------- K4: scatter entries into row-sorted order ----------------
__global__ void scatter_kernel(const int* __restrict__ prc, const float* __restrict__ pw,
                               int* __restrict__ cursor,
                               int* __restrict__ scol, float* __restrict__ sw) {
  const int bn = blockIdx.x;
  const int b = bn >> 10;
  const size_t i = (size_t)bn * NPTS_ + threadIdx.x;
  const int packed = prc[i];
  const int row = packed >> 16, col = packed & 0xFFFF;
  const int pos = atomicAdd(&cursor[b * NN + row], 1);
  scol[(size_t)b * (NN * NPTS_) + pos] = col;
  sw[(size_t)b * (NN * NPTS_) + pos] = pw[i];
}

// ---------------- K5: segment online-softmax attention ----------------
__global__ void __launch_bounds__(512) attn_kernel(
    const float* __restrict__ q, const float* __restrict__ k, const float* __restrict__ v,
    const int* __restrict__ offs, const int* __restrict__ counts,
    const int* __restrict__ scol, const float* __restrict__ sw,
    float* __restrict__ attn) {
  const int bn = blockIdx.x;           // b*N + row
  const int b = bn >> 10, row = bn & 1023;
  const int h = threadIdx.x >> 6, lane = threadIdx.x & 63;
  const int bh = b * NH_ + h;

  const float qj = q[((size_t)bh * NN + row) * EMB_ + lane];
  const int start = offs[b * NN + row];
  const int len = counts[b * NN + row];

  const float* __restrict__ kb = k + (size_t)bh * NN * EMB_;
  const float* __restrict__ vb = v + (size_t)bh * NN * EMB_;
  const int* __restrict__ sc = scol + (size_t)b * (NN * NPTS_);
  const float* __restrict__ swp = sw + (size_t)b * (NN * NPTS_);

  float m = -INFINITY, Z = 0.f, acc = 0.f;
  for (int e = 0; e < len; e++) {
    const int col = sc[start + e];
    const float w = swp[start + e];
    float p = qj * kb[(size_t)col * EMB_ + lane];
    for (int d = 1; d < 64; d <<= 1) p += __shfl_xor(p, d);
    const float logit = w * p;
    const float nm = fmaxf(m, logit);
    const float rs = expf(m - nm);   // 0 when m == -inf
    const float el = expf(logit - nm);
    Z = Z * rs + el;
    acc = acc * rs + el * vb[(size_t)col * EMB_ + lane];
    m = nm;
  }
  const float o = (len > 0) ? acc / Z : 0.f;
  attn[((size_t)bh * NN + row) * EMB_ + lane] = o;
}

// ---------------- K6: output projection ----------------
#define ROWS6 8
__global__ void out_kernel(const float* __restrict__ attn,
                           const float* __restrict__ Wu, const float* __restrict__ bu,
                           float* __restrict__ out) {
  __shared__ float a[ROWS6][NH_ * EMB_];
  const int base = blockIdx.x * ROWS6;
  const int lane = threadIdx.x; // 64
  for (int r = 0; r < ROWS6; r++) {
    const int bn = base + r;
    const int b = bn >> 10, n = bn & 1023;
    for (int h = 0; h < NH_; h++)
      a[r][h * EMB_ + lane] = attn[((size_t)(b * NH_ + h) * NN + n) * EMB_ + lane];
  }
  __syncthreads();
  float acc[ROWS6];
#pragma unroll
  for (int r = 0; r < ROWS6; r++) acc[r] = bu[lane];
  for (int c = 0; c < NH_ * EMB_; c++) {
    const float wv = Wu[c * EMB_ + lane];
#pragma unroll
    for (int r = 0; r < ROWS6; r++) acc[r] += a[r][c] * wv;
  }
  for (int r = 0; r < ROWS6; r++) out[(size_t)(base + r) * EMB_ + lane] = acc[r];
}

// ---------------- host ----------------
extern "C" void kernel_launch(void* const* d_in, const int* in_sizes, int n_in,
                              void* d_out, int out_size, void* d_ws, size_t ws_size,
                              hipStream_t stream) {
  const float* x   = (const float*)d_in[0];
  const float* Wq  = (const float*)d_in[1];
  const float* Wk  = (const float*)d_in[2];
  const float* Wv  = (const float*)d_in[3];
  const float* Wu  = (const float*)d_in[4];
  const float* bu  = (const float*)d_in[5];
  const float* Wp1 = (const float*)d_in[6];
  const float* bp1 = (const float*)d_in[7];
  const float* Wp2 = (const float*)d_in[8];
  const float* bp2 = (const float*)d_in[9];
  const float* mv  = (const float*)d_in[10];
  float* out = (float*)d_out;

  char* ws = (char*)d_ws;
  size_t off = 0;
  auto alloc = [&](size_t bytes) -> void* {
    void* p = ws + off;
    off += (bytes + 255) & ~(size_t)255;
    return p;
  };
  const size_t QKV = (size_t)BH_ * NN * EMB_ * sizeof(float); // 8 MB
  float* q    = (float*)alloc(QKV);
  float* k    = (float*)alloc(QKV);
  float* v    = (float*)alloc(QKV);
  float* attn = (float*)alloc(QKV);
  int*   prc  = (int*)  alloc((size_t)BB * NN * NPTS_ * sizeof(int));
  float* pw   = (float*)alloc((size_t)BB * NN * NPTS_ * sizeof(float));
  int*   counts = (int*)alloc((size_t)BB * NN * sizeof(int));
  int*   offsA  = (int*)alloc((size_t)BB * NN * sizeof(int));
  int*   cursor = (int*)alloc((size_t)BB * NN * sizeof(int));
  int*   scol = (int*)  alloc((size_t)BB * NN * NPTS_ * sizeof(int));
  float* sw   = (float*)alloc((size_t)BB * NN * NPTS_ * sizeof(float));
  if (off > ws_size) return; // insufficient workspace; fail loudly via validation

  // ----- JAX PRNG key derivation (threefry, partitionable semantics) -----
  // skey = key(42) -> (0,42); kg, kl = split(skey): TF(key,(0,0)), TF(key,(0,1))
  // randint internally: k1,k2 = split(key); lower_bits from k2 decide the value
  uint32_t kgA, kgB, klA, klB;
  tf2x32(0u, 42u, 0u, 0u, kgA, kgB);  // kg
  tf2x32(0u, 42u, 0u, 1u, klA, klB);  // kl
  uint32_t kg2A, kg2B, kl2A, kl2B;
  tf2x32(kgA, kgB, 0u, 1u, kg2A, kg2B); // split(kg)[1] -> lower-bits key for glob
  tf2x32(klA, klB, 0u, 1u, kl2A, kl2B); // split(kl)[1] -> lower-bits key for loc

  hipMemsetAsync(counts, 0, (size_t)BB * NN * sizeof(int), stream);

  qkv_kernel<<<(BB * NN) / ROWS1, 256, 0, stream>>>(x, Wq, Wk, Wv, q, k, v);
  points_kernel<<<BB * NN, 64, 0, stream>>>(x, Wp1, bp1, Wp2, bp2, mv,
                                            prc, pw, counts, kg2A, kg2B, kl2A, kl2B);
  scan_kernel<<<BB, NN, 0, stream>>>(counts, offsA, cursor);
  scatter_kernel<<<BB * NN, NPTS_, 0, stream>>>(prc, pw, cursor, scol, sw);
  attn_kernel<<<BB * NN, 512, 0, stream>>>(q, k, v, offsA, counts, scol, sw, attn);
  out_kernel<<<(BB * NN) / ROWS6, 64, 0, stream>>>(attn, Wu, bu, out);
}